// Round 3
// baseline (401.397 us; speedup 1.0000x reference)
//
#include <hip/hip_runtime.h>
#include <hip/hip_bf16.h>
#include <stdint.h>

#define B_ 4
#define T_ 2048
#define C_ 1024
#define NH_ 16
#define HS_ 64

using bf16 = __hip_bfloat16;
typedef __bf16 bf16x8 __attribute__((ext_vector_type(8)));
typedef float f32x4 __attribute__((ext_vector_type(4)));
typedef short short8 __attribute__((ext_vector_type(8)));

__device__ __forceinline__ f32x4 mfma16(bf16x8 a, bf16x8 b, f32x4 c) {
    return __builtin_amdgcn_mfma_f32_16x16x32_bf16(a, b, c, 0, 0, 0);
}

__device__ __forceinline__ short bf16bits(float f) {
    __bf16 b = (__bf16)f;               // RNE f32->bf16
    return *reinterpret_cast<short*>(&b);
}

// load 8 contiguous elements as bf16 bit-pattern
__device__ __forceinline__ short8 load8(const bf16* p) { return *(const short8*)p; }
__device__ __forceinline__ short8 load8(const float* p) {
    float4 f0 = *(const float4*)p;
    float4 f1 = *(const float4*)(p + 4);
    short8 r;
    r[0] = bf16bits(f0.x); r[1] = bf16bits(f0.y); r[2] = bf16bits(f0.z); r[3] = bf16bits(f0.w);
    r[4] = bf16bits(f1.x); r[5] = bf16bits(f1.y); r[6] = bf16bits(f1.z); r[7] = bf16bits(f1.w);
    return r;
}

__device__ __forceinline__ void storev(bf16* p, float v) { *p = __float2bfloat16(v); }
__device__ __forceinline__ void storev(float* p, float v) { *p = v; }

// XOR swizzle for 64B-row LDS tiles (4 x 16B chunks per row)
__device__ __forceinline__ int swz64(int row, int bytecol) {
    return row * 64 + ((((bytecol >> 4) ^ row) & 3) << 4) + (bytecol & 15);
}
// XOR swizzle for 128B-row LDS tiles (8 x 16B chunks per row)
__device__ __forceinline__ int swz128(int row, int bytecol) {
    return row * 128 + ((((bytecol >> 4) ^ row) & 7) << 4) + (bytecol & 15);
}

// ---------------- transpose: out[c][r] = bf16(in[r][c]), 64x64 tiles -------
template <typename InT>
__global__ __launch_bounds__(256) void transpose_kernel(
    const InT* __restrict__ in, bf16* __restrict__ out, int R, int C)
{
    __shared__ short tile[64][80];
    const int t = threadIdx.x;
    const size_t batch = (size_t)blockIdx.z * R * C;
    const int bx = blockIdx.x * 64;
    const int by = blockIdx.y * 64;
    const int r = t >> 3, c8 = (t & 7) * 8;

    *(short8*)&tile[r][c8]      = load8(in + batch + (size_t)(by + r) * C + bx + c8);
    *(short8*)&tile[r + 32][c8] = load8(in + batch + (size_t)(by + r + 32) * C + bx + c8);
    __syncthreads();
    short8 v0, v1;
    #pragma unroll
    for (int i = 0; i < 8; ++i) {
        v0[i] = tile[c8 + i][r];
        v1[i] = tile[c8 + i][r + 32];
    }
    *(short8*)((bf16*)out + (size_t)blockIdx.z * R * C + (size_t)(bx + r) * R + by + c8)      = v0;
    *(short8*)((bf16*)out + (size_t)blockIdx.z * R * C + (size_t)(bx + r + 32) * R + by + c8) = v1;
}

// ---------------- GEMM: out = bf16(A[M,K]) @ B + bias, B given as BT[N,K] --
// MODE 0: out[m*N+n] row-major.  MODE 1: split-head out[((b*NH+h)*T+t)*HS+d]
template <int MODE, typename AT, typename OutT>
__global__ __launch_bounds__(256) void gemm_bias_kernel(
    const AT* __restrict__ A, const bf16* __restrict__ BT,
    const float* __restrict__ bias, OutT* __restrict__ out,
    int M, int N, int K)
{
    __shared__ short As[128 * 32];
    __shared__ short Bs[128 * 32];
    const int tid = threadIdx.x;
    const int lane = tid & 63;
    const int w = tid >> 6;
    const int wm = w >> 1, wn = w & 1;        // 2x2 waves, 64x64 each
    const int lg = lane >> 4, lr = lane & 15;
    const int bm = blockIdx.x * 128;
    const int bn = blockIdx.y * 128;

    const int sr = tid >> 2;                  // staging row 0..63
    const int sc = (tid & 3) * 16;            // staging byte col
    const AT*   gA = A  + (size_t)(bm + sr) * K + (tid & 3) * 8;
    const bf16* gB = BT + (size_t)(bn + sr) * K + (tid & 3) * 8;

    f32x4 acc[4][4] = {};

    for (int k0 = 0; k0 < K; k0 += 32) {
        __syncthreads();
        {
            short8 a0 = load8(gA + k0);
            short8 a1 = load8(gA + (size_t)64 * K + k0);
            short8 b0 = load8(gB + k0);
            short8 b1 = load8(gB + (size_t)64 * K + k0);
            *(short8*)((char*)As + swz64(sr, sc))      = a0;
            *(short8*)((char*)As + swz64(sr + 64, sc)) = a1;
            *(short8*)((char*)Bs + swz64(sr, sc))      = b0;
            *(short8*)((char*)Bs + swz64(sr + 64, sc)) = b1;
        }
        __syncthreads();
        bf16x8 af[4], bfv[4];
        #pragma unroll
        for (int i = 0; i < 4; ++i) {
            af[i]  = *(const bf16x8*)((char*)As + swz64(wm * 64 + i * 16 + lr, lg * 16));
            bfv[i] = *(const bf16x8*)((char*)Bs + swz64(wn * 64 + i * 16 + lr, lg * 16));
        }
        #pragma unroll
        for (int mi = 0; mi < 4; ++mi)
            #pragma unroll
            for (int nj = 0; nj < 4; ++nj)
                acc[mi][nj] = mfma16(af[mi], bfv[nj], acc[mi][nj]);
    }

    #pragma unroll
    for (int mi = 0; mi < 4; ++mi) {
        #pragma unroll
        for (int nj = 0; nj < 4; ++nj) {
            const int n = bn + wn * 64 + nj * 16 + lr;
            const float bv = bias[n];
            #pragma unroll
            for (int r = 0; r < 4; ++r) {
                const int m = bm + wm * 64 + mi * 16 + lg * 4 + r;
                const float val = acc[mi][nj][r] + bv;
                size_t idx;
                if (MODE == 1) {
                    idx = (size_t)((m >> 11) * NH_ + (n >> 6)) * (T_ * HS_)
                        + (size_t)(m & (T_ - 1)) * HS_ + (n & (HS_ - 1));
                } else {
                    idx = (size_t)m * N + n;
                }
                storev(out + idx, val);
            }
        }
    }
}

// ---------------- causal flash attention --------------------------------
// Qh,Kh: [B*NH][T][HS] bf16.  Vt: [B*NH][HS][T] bf16 (pre-transposed).
// Ob: [B][T][NH][HS] bf16.  4 independent waves per block, 16 q-rows each.
__global__ __launch_bounds__(256) void attn_kernel(
    const bf16* __restrict__ Qh, const bf16* __restrict__ Kh,
    const bf16* __restrict__ Vt, bf16* __restrict__ Ob)
{
    __shared__ __bf16 Ps[4][16 * 64];     // per-wave P tile (swizzled rows)
    const int tid  = threadIdx.x;
    const int lane = tid & 63;
    const int w    = tid >> 6;
    const int lg = lane >> 4, lr = lane & 15;
    const int bh = blockIdx.x;            // 0..63  (b*NH + h)
    const int qb = 31 - blockIdx.y;       // heavy q-blocks dispatched first
    const int q0 = qb * 64 + w * 16;
    const size_t hb = (size_t)bh * (T_ * HS_);

    bf16x8 aQ[2];
    #pragma unroll
    for (int f = 0; f < 2; ++f)
        aQ[f] = *(const bf16x8*)(Qh + hb + (size_t)(q0 + lr) * HS_ + f * 32 + lg * 8);

    f32x4 accO[4] = {};
    float m_r[4], l_r[4];
    #pragma unroll
    for (int r = 0; r < 4; ++r) { m_r[r] = -1e30f; l_r[r] = 0.f; }

    __bf16* pw = &Ps[w][0];

    for (int kb = 0; kb <= qb; ++kb) {
        const int j0 = kb * 64;
        // ---- S = (Q K^T) / 8 ; S tile layout: row=4*lg+r (q), col=lr (j) --
        float s[4][4];
        #pragma unroll
        for (int sub = 0; sub < 4; ++sub) {
            f32x4 acc = {};
            #pragma unroll
            for (int kf = 0; kf < 2; ++kf) {
                bf16x8 bK = *(const bf16x8*)(Kh + hb + (size_t)(j0 + sub * 16 + lr) * HS_ + kf * 32 + lg * 8);
                acc = mfma16(aQ[kf], bK, acc);
            }
            #pragma unroll
            for (int r = 0; r < 4; ++r) s[sub][r] = acc[r] * 0.125f;
        }
        if (kb == qb) {   // diagonal block: hard causal mask
            #pragma unroll
            for (int sub = 0; sub < 4; ++sub)
                #pragma unroll
                for (int r = 0; r < 4; ++r)
                    if (sub * 16 + lr > w * 16 + lg * 4 + r) s[sub][r] = -1e30f;
        }
        // ---- online softmax (rows = 4*lg+r, reduce over 16 lanes = cols) --
        float sf[4];
        #pragma unroll
        for (int r = 0; r < 4; ++r) {
            float mx = fmaxf(fmaxf(s[0][r], s[1][r]), fmaxf(s[2][r], s[3][r]));
            mx = fmaxf(mx, __shfl_xor(mx, 1));
            mx = fmaxf(mx, __shfl_xor(mx, 2));
            mx = fmaxf(mx, __shfl_xor(mx, 4));
            mx = fmaxf(mx, __shfl_xor(mx, 8));
            const float mnew = fmaxf(m_r[r], mx);
            sf[r] = __expf(m_r[r] - mnew);
            m_r[r] = mnew;
            float rs = 0.f;
            #pragma unroll
            for (int sub = 0; sub < 4; ++sub) {
                const float p = __expf(s[sub][r] - mnew);
                s[sub][r] = p;
                rs += p;
            }
            rs += __shfl_xor(rs, 1);
            rs += __shfl_xor(rs, 2);
            rs += __shfl_xor(rs, 4);
            rs += __shfl_xor(rs, 8);
            l_r[r] = l_r[r] * sf[r] + rs;
            #pragma unroll
            for (int d = 0; d < 4; ++d) accO[d][r] *= sf[r];
        }
        // ---- P -> LDS (bf16, swizzled), wave-internal only ----------------
        #pragma unroll
        for (int sub = 0; sub < 4; ++sub)
            #pragma unroll
            for (int r = 0; r < 4; ++r)
                *(__bf16*)((char*)pw + swz128(lg * 4 + r, (sub * 16 + lr) * 2)) = (__bf16)s[sub][r];
        __builtin_amdgcn_wave_barrier();
        bf16x8 aP[2];
        #pragma unroll
        for (int kf = 0; kf < 2; ++kf)
            aP[kf] = *(const bf16x8*)((char*)pw + swz128(lr, (kf * 32 + lg * 8) * 2));
        __builtin_amdgcn_wave_barrier();
        // ---- O += P @ V  (V^T fragments straight from global/L2) ----------
        #pragma unroll
        for (int dsub = 0; dsub < 4; ++dsub) {
            #pragma unroll
            for (int kf = 0; kf < 2; ++kf) {
                bf16x8 bV = *(const bf16x8*)(Vt + hb + (size_t)(dsub * 16 + lr) * T_ + j0 + kf * 32 + lg * 8);
                accO[dsub] = mfma16(aP[kf], bV, accO[dsub]);
            }
        }
    }
    // ---- epilogue: Ob[b][t][h][d] = O / l ---------------------------------
    const int b = bh >> 4, h = bh & 15;
    #pragma unroll
    for (int dsub = 0; dsub < 4; ++dsub) {
        #pragma unroll
        for (int r = 0; r < 4; ++r) {
            const int q = q0 + lg * 4 + r;
            const float o = accO[dsub][r] / l_r[r];
            Ob[(((size_t)b * T_ + q) * NH_ + h) * HS_ + dsub * 16 + lr] = __float2bfloat16(o);
        }
    }
}

// ---------------- launch ----------------------------------------------------
extern "C" void kernel_launch(void* const* d_in, const int* in_sizes, int n_in,
                              void* d_out, int out_size, void* d_ws, size_t ws_size,
                              hipStream_t stream)
{
    (void)in_sizes; (void)n_in; (void)out_size; (void)ws_size;
    const float* Xq = (const float*)d_in[0];
    const float* Xk = (const float*)d_in[1];
    const float* Xv = (const float*)d_in[2];
    // d_in[3] = mask: known causal triu(k=1); implemented analytically.
    const float* Wq = (const float*)d_in[4];
    const float* bq = (const float*)d_in[5];
    const float* Wk = (const float*)d_in[6];
    const float* bk = (const float*)d_in[7];
    const float* Wv = (const float*)d_in[8];
    const float* bv = (const float*)d_in[9];
    const float* Wo = (const float*)d_in[10];
    const float* bo = (const float*)d_in[11];

    char* ws = (char*)d_ws;
    bf16* WqT = (bf16*)(ws + ((size_t)0  << 20));  // 2MB each (bf16 transposed)
    bf16* WkT = (bf16*)(ws + ((size_t)2  << 20));
    bf16* WvT = (bf16*)(ws + ((size_t)4  << 20));
    bf16* WoT = (bf16*)(ws + ((size_t)6  << 20));
    bf16* Qh  = (bf16*)(ws + ((size_t)8  << 20));  // 16MB each
    bf16* Kh  = (bf16*)(ws + ((size_t)24 << 20));
    bf16* Vh  = (bf16*)(ws + ((size_t)40 << 20));
    bf16* VtG = (bf16*)(ws + ((size_t)56 << 20));
    bf16* Ob  = (bf16*)(ws + ((size_t)72 << 20));  // ends at 88MB

    dim3 blk(256);
    transpose_kernel<float><<<dim3(16, 16, 1), blk, 0, stream>>>(Wq, WqT, 1024, 1024);
    transpose_kernel<float><<<dim3(16, 16, 1), blk, 0, stream>>>(Wk, WkT, 1024, 1024);
    transpose_kernel<float><<<dim3(16, 16, 1), blk, 0, stream>>>(Wv, WvT, 1024, 1024);
    transpose_kernel<float><<<dim3(16, 16, 1), blk, 0, stream>>>(Wo, WoT, 1024, 1024);

    gemm_bias_kernel<1, float, bf16><<<dim3(64, 8), blk, 0, stream>>>(Xq, WqT, bq, Qh, 8192, 1024, 1024);
    gemm_bias_kernel<1, float, bf16><<<dim3(64, 8), blk, 0, stream>>>(Xk, WkT, bk, Kh, 8192, 1024, 1024);
    gemm_bias_kernel<1, float, bf16><<<dim3(64, 8), blk, 0, stream>>>(Xv, WvT, bv, Vh, 8192, 1024, 1024);

    // per-head V transpose: [bh][t][d] -> [bh][d][t]
    transpose_kernel<bf16><<<dim3(1, 32, B_ * NH_), blk, 0, stream>>>(Vh, VtG, T_, HS_);

    attn_kernel<<<dim3(64, 32), blk, 0, stream>>>(Qh, Kh, VtG, Ob);

    // final projection written as FLOAT32 (reference output dtype)
    gemm_bias_kernel<0, bf16, float><<<dim3(64, 8), blk, 0, stream>>>(Ob, WoT, bo, (float*)d_out, 8192, 1024, 1024);
}

// Round 6
// 290.865 us; speedup vs baseline: 1.3800x; 1.3800x over previous
//
#include <hip/hip_runtime.h>
#include <hip/hip_bf16.h>
#include <stdint.h>

#define B_ 4
#define T_ 2048
#define C_ 1024
#define NH_ 16
#define HS_ 64

using bf16 = __hip_bfloat16;
typedef __bf16 bf16x8 __attribute__((ext_vector_type(8)));
typedef float f32x4 __attribute__((ext_vector_type(4)));
typedef short short8 __attribute__((ext_vector_type(8)));

__device__ __forceinline__ f32x4 mfma16(bf16x8 a, bf16x8 b, f32x4 c) {
    return __builtin_amdgcn_mfma_f32_16x16x32_bf16(a, b, c, 0, 0, 0);
}

__device__ __forceinline__ float fexp2(float x) {
    return __builtin_amdgcn_exp2f(x);   // v_exp_f32: 2^x
}

__device__ __forceinline__ short bf16bits(float f) {
    __bf16 b = (__bf16)f;               // RNE f32->bf16
    return *reinterpret_cast<short*>(&b);
}

// load 8 contiguous elements as bf16 bit-pattern
__device__ __forceinline__ short8 load8(const bf16* p) { return *(const short8*)p; }
__device__ __forceinline__ short8 load8(const float* p) {
    float4 f0 = *(const float4*)p;
    float4 f1 = *(const float4*)(p + 4);
    short8 r;
    r[0] = bf16bits(f0.x); r[1] = bf16bits(f0.y); r[2] = bf16bits(f0.z); r[3] = bf16bits(f0.w);
    r[4] = bf16bits(f1.x); r[5] = bf16bits(f1.y); r[6] = bf16bits(f1.z); r[7] = bf16bits(f1.w);
    return r;
}

__device__ __forceinline__ void storev(bf16* p, float v) { *p = __float2bfloat16(v); }
__device__ __forceinline__ void storev(float* p, float v) { *p = v; }

// XOR swizzle for 64B-row LDS tiles (4 x 16B chunks per row)
__device__ __forceinline__ int swz64(int row, int bytecol) {
    return row * 64 + ((((bytecol >> 4) ^ row) & 3) << 4) + (bytecol & 15);
}

// ---------------- transpose: out[c][r] = bf16(in[r][c]), 64x64 tiles -------
template <typename InT>
__global__ __launch_bounds__(256) void transpose_kernel(
    const InT* __restrict__ in, bf16* __restrict__ out, int R, int C)
{
    __shared__ short tile[64][80];
    const int t = threadIdx.x;
    const size_t batch = (size_t)blockIdx.z * R * C;
    const int bx = blockIdx.x * 64;
    const int by = blockIdx.y * 64;
    const int r = t >> 3, c8 = (t & 7) * 8;

    *(short8*)&tile[r][c8]      = load8(in + batch + (size_t)(by + r) * C + bx + c8);
    *(short8*)&tile[r + 32][c8] = load8(in + batch + (size_t)(by + r + 32) * C + bx + c8);
    __syncthreads();
    short8 v0, v1;
    #pragma unroll
    for (int i = 0; i < 8; ++i) {
        v0[i] = tile[c8 + i][r];
        v1[i] = tile[c8 + i][r + 32];
    }
    *(short8*)((bf16*)out + (size_t)blockIdx.z * R * C + (size_t)(bx + r) * R + by + c8)      = v0;
    *(short8*)((bf16*)out + (size_t)blockIdx.z * R * C + (size_t)(bx + r + 32) * R + by + c8) = v1;
}

// ---------------- GEMM: out = bf16(A[M,K]) @ B + bias, B given as BT[N,K] --
// MODE 0: out[m*N+n] row-major.  MODE 1: split-head out[((b*NH+h)*T+t)*HS+d]
template <int MODE, typename AT, typename OutT>
__global__ __launch_bounds__(256) void gemm_bias_kernel(
    const AT* __restrict__ A, const bf16* __restrict__ BT,
    const float* __restrict__ bias, OutT* __restrict__ out,
    int M, int N, int K)
{
    __shared__ short As[128 * 32];
    __shared__ short Bs[128 * 32];
    const int tid = threadIdx.x;
    const int lane = tid & 63;
    const int w = tid >> 6;
    const int wm = w >> 1, wn = w & 1;        // 2x2 waves, 64x64 each
    const int lg = lane >> 4, lr = lane & 15;
    const int bm = blockIdx.x * 128;
    const int bn = blockIdx.y * 128;

    const int sr = tid >> 2;                  // staging row 0..63
    const int sc = (tid & 3) * 16;            // staging byte col
    const AT*   gA = A  + (size_t)(bm + sr) * K + (tid & 3) * 8;
    const bf16* gB = BT + (size_t)(bn + sr) * K + (tid & 3) * 8;

    f32x4 acc[4][4] = {};

    for (int k0 = 0; k0 < K; k0 += 32) {
        __syncthreads();
        {
            short8 a0 = load8(gA + k0);
            short8 a1 = load8(gA + (size_t)64 * K + k0);
            short8 b0 = load8(gB + k0);
            short8 b1 = load8(gB + (size_t)64 * K + k0);
            *(short8*)((char*)As + swz64(sr, sc))      = a0;
            *(short8*)((char*)As + swz64(sr + 64, sc)) = a1;
            *(short8*)((char*)Bs + swz64(sr, sc))      = b0;
            *(short8*)((char*)Bs + swz64(sr + 64, sc)) = b1;
        }
        __syncthreads();
        bf16x8 af[4], bfv[4];
        #pragma unroll
        for (int i = 0; i < 4; ++i) {
            af[i]  = *(const bf16x8*)((char*)As + swz64(wm * 64 + i * 16 + lr, lg * 16));
            bfv[i] = *(const bf16x8*)((char*)Bs + swz64(wn * 64 + i * 16 + lr, lg * 16));
        }
        #pragma unroll
        for (int mi = 0; mi < 4; ++mi)
            #pragma unroll
            for (int nj = 0; nj < 4; ++nj)
                acc[mi][nj] = mfma16(af[mi], bfv[nj], acc[mi][nj]);
    }

    #pragma unroll
    for (int mi = 0; mi < 4; ++mi) {
        #pragma unroll
        for (int nj = 0; nj < 4; ++nj) {
            const int n = bn + wn * 64 + nj * 16 + lr;
            const float bv = bias[n];
            #pragma unroll
            for (int r = 0; r < 4; ++r) {
                const int m = bm + wm * 64 + mi * 16 + lg * 4 + r;
                const float val = acc[mi][nj][r] + bv;
                size_t idx;
                if (MODE == 1) {
                    idx = (size_t)((m >> 11) * NH_ + (n >> 6)) * (T_ * HS_)
                        + (size_t)(m & (T_ - 1)) * HS_ + (n & (HS_ - 1));
                } else {
                    idx = (size_t)m * N + n;
                }
                storev(out + idx, val);
            }
        }
    }
}

// ---------------- causal flash attention (swapped QK^T, in-lane softmax) ---
// Qh,Kh: [B*NH][T][HS] bf16.  Vt: [B*NH][HS][T] bf16 (pre-transposed).
// Ob: [B][T][NH][HS] bf16.  4 waves/block, 32 q-rows each (block = 128 q).
// S^T = mfma(K_frag, Q_frag): lane owns q = lane&15; k = s*16+4*lg+r in-lane.
// accO rows are q = 4*lg+r (C/D layout) -> rescale factors must be shuffled
// from the softmax-owner lane (4*lg+r) before scaling accO.
__global__ __launch_bounds__(256) void attn_kernel(
    const bf16* __restrict__ Qh, const bf16* __restrict__ Kh,
    const bf16* __restrict__ Vt, bf16* __restrict__ Ob)
{
    __shared__ char Ps[4][2][2048];       // per wave, per q-subtile: 16x64 bf16
    const int tid  = threadIdx.x;
    const int lane = tid & 63;
    const int w    = tid >> 6;
    const int lg = lane >> 4, lr = lane & 15;
    const int bh = blockIdx.x;            // b*NH + h
    const int qB = (int)(gridDim.y - 1 - blockIdx.y) * 128;  // heavy first
    const int q0w = qB + w * 32;
    const size_t hb = (size_t)bh * (T_ * HS_);
    const int swzr = (lr & 7) << 4;
    // fold 1/sqrt(HS) and log2(e) into one scale; softmax in base-2 domain
    const float SC = 0.125f * 1.44269504088896f;

    bf16x8 qf[2][2];
    #pragma unroll
    for (int qs = 0; qs < 2; ++qs)
        #pragma unroll
        for (int kfi = 0; kfi < 2; ++kfi)
            qf[qs][kfi] = *(const bf16x8*)(Qh + hb + (size_t)(q0w + qs * 16 + lr) * HS_ + kfi * 32 + lg * 8);

    f32x4 accO[2][4] = {};
    float m_s[2] = {-1e30f, -1e30f};
    float l_s[2] = {0.f, 0.f};
    char* pwq[2] = {&Ps[w][0][0], &Ps[w][1][0]};

    for (int j0 = 0; j0 <= q0w + 31; j0 += 64) {
        // K and V fragments for this 64-wide k-tile (shared by both q-subtiles)
        bf16x8 kfr[4][2], vfr[4][2];
        #pragma unroll
        for (int s = 0; s < 4; ++s)
            #pragma unroll
            for (int kfi = 0; kfi < 2; ++kfi)
                kfr[s][kfi] = *(const bf16x8*)(Kh + hb + (size_t)(j0 + s * 16 + lr) * HS_ + kfi * 32 + lg * 8);
        #pragma unroll
        for (int d = 0; d < 4; ++d)
            #pragma unroll
            for (int kfi = 0; kfi < 2; ++kfi)
                vfr[d][kfi] = *(const bf16x8*)(Vt + hb + (size_t)(d * 16 + lr) * T_ + j0 + kfi * 32 + lg * 8);

        const bool domask = (j0 + 63 > q0w);

        #pragma unroll
        for (int qs = 0; qs < 2; ++qs) {
            // S^T: col=q (lane&15), row=k-within-16 (4*lg+r)
            f32x4 st[4];
            #pragma unroll
            for (int s = 0; s < 4; ++s) {
                f32x4 a = {};
                #pragma unroll
                for (int kfi = 0; kfi < 2; ++kfi)
                    a = mfma16(kfr[s][kfi], qf[qs][kfi], a);
                st[s] = a;
            }
            float p[4][4];
            #pragma unroll
            for (int s = 0; s < 4; ++s)
                #pragma unroll
                for (int r = 0; r < 4; ++r)
                    p[s][r] = st[s][r] * SC;
            if (domask) {
                const int q = q0w + qs * 16 + lr;
                #pragma unroll
                for (int s = 0; s < 4; ++s)
                    #pragma unroll
                    for (int r = 0; r < 4; ++r)
                        if (j0 + s * 16 + 4 * lg + r > q) p[s][r] = -1e30f;
            }
            // row max: in-lane tree + 2 cross-group shuffles (row = q = lr)
            float mx01 = fmaxf(fmaxf(p[0][0], p[0][1]), fmaxf(p[0][2], p[0][3]));
            float mx11 = fmaxf(fmaxf(p[1][0], p[1][1]), fmaxf(p[1][2], p[1][3]));
            float mx21 = fmaxf(fmaxf(p[2][0], p[2][1]), fmaxf(p[2][2], p[2][3]));
            float mx31 = fmaxf(fmaxf(p[3][0], p[3][1]), fmaxf(p[3][2], p[3][3]));
            float mx = fmaxf(fmaxf(mx01, mx11), fmaxf(mx21, mx31));
            mx = fmaxf(mx, __shfl_xor(mx, 16));
            mx = fmaxf(mx, __shfl_xor(mx, 32));
            const float mnew = fmaxf(m_s[qs], mx);
            const float sf = fexp2(m_s[qs] - mnew);
            m_s[qs] = mnew;
            float rs = 0.f;
            #pragma unroll
            for (int s = 0; s < 4; ++s)
                #pragma unroll
                for (int r = 0; r < 4; ++r) {
                    p[s][r] = fexp2(p[s][r] - mnew);
                    rs += p[s][r];
                }
            rs += __shfl_xor(rs, 16);
            rs += __shfl_xor(rs, 32);
            l_s[qs] = l_s[qs] * sf + rs;
            // redistribute sf to accO rows (accO row r belongs to q=4*lg+r,
            // whose softmax owner is lane 4*lg+r; sf uniform across lg-groups)
            f32x4 sfv;
            #pragma unroll
            for (int r = 0; r < 4; ++r)
                sfv[r] = __shfl(sf, 4 * lg + r);
            #pragma unroll
            for (int d = 0; d < 4; ++d)
                accO[qs][d] *= sfv;
            // pack 4 consecutive-k bf16 and write 8B (swizzled)
            #pragma unroll
            for (int s = 0; s < 4; ++s) {
                uint2 pk;
                pk.x = (uint16_t)bf16bits(p[s][0]) | ((uint32_t)(uint16_t)bf16bits(p[s][1]) << 16);
                pk.y = (uint16_t)bf16bits(p[s][2]) | ((uint32_t)(uint16_t)bf16bits(p[s][3]) << 16);
                *(uint2*)(pwq[qs] + ((lr * 128 + s * 32 + lg * 8) ^ swzr)) = pk;
            }
        }
        __builtin_amdgcn_wave_barrier();
        bf16x8 aP[2][2];
        #pragma unroll
        for (int qs = 0; qs < 2; ++qs)
            #pragma unroll
            for (int kfi = 0; kfi < 2; ++kfi)
                aP[qs][kfi] = *(const bf16x8*)(pwq[qs] + ((lr * 128 + kfi * 64 + lg * 16) ^ swzr));
        __builtin_amdgcn_wave_barrier();
        #pragma unroll
        for (int qs = 0; qs < 2; ++qs)
            #pragma unroll
            for (int d = 0; d < 4; ++d)
                #pragma unroll
                for (int kfi = 0; kfi < 2; ++kfi)
                    accO[qs][d] = mfma16(aP[qs][kfi], vfr[d][kfi], accO[qs][d]);
    }

    // epilogue: redistribute l (owner lane lr==q') then write Ob[b][t][h][d]
    const int b = bh >> 4, h = bh & 15;
    #pragma unroll
    for (int qs = 0; qs < 2; ++qs) {
        float lsv[4];
        #pragma unroll
        for (int r = 0; r < 4; ++r)
            lsv[r] = __shfl(l_s[qs], 4 * lg + r);
        #pragma unroll
        for (int d = 0; d < 4; ++d)
            #pragma unroll
            for (int r = 0; r < 4; ++r) {
                const int q = q0w + qs * 16 + 4 * lg + r;
                const float o = accO[qs][d][r] / lsv[r];
                Ob[(((size_t)b * T_ + q) * NH_ + h) * HS_ + d * 16 + lr] = __float2bfloat16(o);
            }
    }
}

// ---------------- launch ----------------------------------------------------
extern "C" void kernel_launch(void* const* d_in, const int* in_sizes, int n_in,
                              void* d_out, int out_size, void* d_ws, size_t ws_size,
                              hipStream_t stream)
{
    (void)in_sizes; (void)n_in; (void)out_size; (void)ws_size;
    const float* Xq = (const float*)d_in[0];
    const float* Xk = (const float*)d_in[1];
    const float* Xv = (const float*)d_in[2];
    // d_in[3] = mask: known causal triu(k=1); implemented analytically.
    const float* Wq = (const float*)d_in[4];
    const float* bq = (const float*)d_in[5];
    const float* Wk = (const float*)d_in[6];
    const float* bk = (const float*)d_in[7];
    const float* Wv = (const float*)d_in[8];
    const float* bv = (const float*)d_in[9];
    const float* Wo = (const float*)d_in[10];
    const float* bo = (const float*)d_in[11];

    char* ws = (char*)d_ws;
    bf16* WqT = (bf16*)(ws + ((size_t)0  << 20));  // 2MB each (bf16 transposed)
    bf16* WkT = (bf16*)(ws + ((size_t)2  << 20));
    bf16* WvT = (bf16*)(ws + ((size_t)4  << 20));
    bf16* WoT = (bf16*)(ws + ((size_t)6  << 20));
    bf16* Qh  = (bf16*)(ws + ((size_t)8  << 20));  // 16MB each
    bf16* Kh  = (bf16*)(ws + ((size_t)24 << 20));
    bf16* Vh  = (bf16*)(ws + ((size_t)40 << 20));
    bf16* VtG = (bf16*)(ws + ((size_t)56 << 20));
    bf16* Ob  = (bf16*)(ws + ((size_t)72 << 20));  // ends at 88MB

    dim3 blk(256);
    transpose_kernel<float><<<dim3(16, 16, 1), blk, 0, stream>>>(Wq, WqT, 1024, 1024);
    transpose_kernel<float><<<dim3(16, 16, 1), blk, 0, stream>>>(Wk, WkT, 1024, 1024);
    transpose_kernel<float><<<dim3(16, 16, 1), blk, 0, stream>>>(Wv, WvT, 1024, 1024);
    transpose_kernel<float><<<dim3(16, 16, 1), blk, 0, stream>>>(Wo, WoT, 1024, 1024);

    gemm_bias_kernel<1, float, bf16><<<dim3(64, 8), blk, 0, stream>>>(Xq, WqT, bq, Qh, 8192, 1024, 1024);
    gemm_bias_kernel<1, float, bf16><<<dim3(64, 8), blk, 0, stream>>>(Xk, WkT, bk, Kh, 8192, 1024, 1024);
    gemm_bias_kernel<1, float, bf16><<<dim3(64, 8), blk, 0, stream>>>(Xv, WvT, bv, Vh, 8192, 1024, 1024);

    // per-head V transpose: [bh][t][d] -> [bh][d][t]
    transpose_kernel<bf16><<<dim3(1, 32, B_ * NH_), blk, 0, stream>>>(Vh, VtG, T_, HS_);

    attn_kernel<<<dim3(64, 16), blk, 0, stream>>>(Qh, Kh, VtG, Ob);

    // final projection written as FLOAT32 (reference output dtype)
    gemm_bias_kernel<0, bf16, float><<<dim3(64, 8), blk, 0, stream>>>(Ob, WoT, bo, (float*)d_out, 8192, 1024, 1024);
}

// Round 7
// 277.198 us; speedup vs baseline: 1.4481x; 1.0493x over previous
//
#include <hip/hip_runtime.h>
#include <hip/hip_bf16.h>
#include <stdint.h>

#define B_ 4
#define T_ 2048
#define C_ 1024
#define NH_ 16
#define HS_ 64

using bf16 = __hip_bfloat16;
typedef __bf16 bf16x8 __attribute__((ext_vector_type(8)));
typedef float f32x4 __attribute__((ext_vector_type(4)));
typedef short short8 __attribute__((ext_vector_type(8)));

__device__ __forceinline__ f32x4 mfma16(bf16x8 a, bf16x8 b, f32x4 c) {
    return __builtin_amdgcn_mfma_f32_16x16x32_bf16(a, b, c, 0, 0, 0);
}

__device__ __forceinline__ float fexp2(float x) {
    return __builtin_amdgcn_exp2f(x);   // v_exp_f32: 2^x
}

__device__ __forceinline__ short bf16bits(float f) {
    __bf16 b = (__bf16)f;               // RNE f32->bf16
    return *reinterpret_cast<short*>(&b);
}

// load 8 contiguous elements as bf16 bit-pattern
__device__ __forceinline__ short8 load8(const bf16* p) { return *(const short8*)p; }
__device__ __forceinline__ short8 load8(const float* p) {
    float4 f0 = *(const float4*)p;
    float4 f1 = *(const float4*)(p + 4);
    short8 r;
    r[0] = bf16bits(f0.x); r[1] = bf16bits(f0.y); r[2] = bf16bits(f0.z); r[3] = bf16bits(f0.w);
    r[4] = bf16bits(f1.x); r[5] = bf16bits(f1.y); r[6] = bf16bits(f1.z); r[7] = bf16bits(f1.w);
    return r;
}

__device__ __forceinline__ void storev(bf16* p, float v) { *p = __float2bfloat16(v); }
__device__ __forceinline__ void storev(float* p, float v) { *p = v; }

// XOR swizzle for 64B-row LDS tiles (4 x 16B chunks per row)
__device__ __forceinline__ int swz64(int row, int bytecol) {
    return row * 64 + ((((bytecol >> 4) ^ row) & 3) << 4) + (bytecol & 15);
}

// ---------------- transpose: out[c][r] = bf16(in[r][c]), 64x64 tiles -------
template <typename InT>
__global__ __launch_bounds__(256) void transpose_kernel(
    const InT* __restrict__ in, bf16* __restrict__ out, int R, int C)
{
    __shared__ short tile[64][80];
    const int t = threadIdx.x;
    const size_t batch = (size_t)blockIdx.z * R * C;
    const int bx = blockIdx.x * 64;
    const int by = blockIdx.y * 64;
    const int r = t >> 3, c8 = (t & 7) * 8;

    *(short8*)&tile[r][c8]      = load8(in + batch + (size_t)(by + r) * C + bx + c8);
    *(short8*)&tile[r + 32][c8] = load8(in + batch + (size_t)(by + r + 32) * C + bx + c8);
    __syncthreads();
    short8 v0, v1;
    #pragma unroll
    for (int i = 0; i < 8; ++i) {
        v0[i] = tile[c8 + i][r];
        v1[i] = tile[c8 + i][r + 32];
    }
    *(short8*)((bf16*)out + (size_t)blockIdx.z * R * C + (size_t)(bx + r) * R + by + c8)      = v0;
    *(short8*)((bf16*)out + (size_t)blockIdx.z * R * C + (size_t)(bx + r + 32) * R + by + c8) = v1;
}

// ---------------- GEMM: out = bf16(A[M,K]) @ B + bias, B given as BT[N,K] --
// MODE 0: out[m*N+n] row-major.  MODE 1: split-head out[((b*NH+h)*T+t)*HS+d]
template <int MODE, typename AT, typename OutT>
__global__ __launch_bounds__(256) void gemm_bias_kernel(
    const AT* __restrict__ A, const bf16* __restrict__ BT,
    const float* __restrict__ bias, OutT* __restrict__ out,
    int M, int N, int K)
{
    __shared__ short As[128 * 32];
    __shared__ short Bs[128 * 32];
    const int tid = threadIdx.x;
    const int lane = tid & 63;
    const int w = tid >> 6;
    const int wm = w >> 1, wn = w & 1;        // 2x2 waves, 64x64 each
    const int lg = lane >> 4, lr = lane & 15;
    const int bm = blockIdx.x * 128;
    const int bn = blockIdx.y * 128;

    const int sr = tid >> 2;                  // staging row 0..63
    const int sc = (tid & 3) * 16;            // staging byte col
    const AT*   gA = A  + (size_t)(bm + sr) * K + (tid & 3) * 8;
    const bf16* gB = BT + (size_t)(bn + sr) * K + (tid & 3) * 8;

    f32x4 acc[4][4] = {};

    for (int k0 = 0; k0 < K; k0 += 32) {
        __syncthreads();
        {
            short8 a0 = load8(gA + k0);
            short8 a1 = load8(gA + (size_t)64 * K + k0);
            short8 b0 = load8(gB + k0);
            short8 b1 = load8(gB + (size_t)64 * K + k0);
            *(short8*)((char*)As + swz64(sr, sc))      = a0;
            *(short8*)((char*)As + swz64(sr + 64, sc)) = a1;
            *(short8*)((char*)Bs + swz64(sr, sc))      = b0;
            *(short8*)((char*)Bs + swz64(sr + 64, sc)) = b1;
        }
        __syncthreads();
        bf16x8 af[4], bfv[4];
        #pragma unroll
        for (int i = 0; i < 4; ++i) {
            af[i]  = *(const bf16x8*)((char*)As + swz64(wm * 64 + i * 16 + lr, lg * 16));
            bfv[i] = *(const bf16x8*)((char*)Bs + swz64(wn * 64 + i * 16 + lr, lg * 16));
        }
        #pragma unroll
        for (int mi = 0; mi < 4; ++mi)
            #pragma unroll
            for (int nj = 0; nj < 4; ++nj)
                acc[mi][nj] = mfma16(af[mi], bfv[nj], acc[mi][nj]);
    }

    #pragma unroll
    for (int mi = 0; mi < 4; ++mi) {
        #pragma unroll
        for (int nj = 0; nj < 4; ++nj) {
            const int n = bn + wn * 64 + nj * 16 + lr;
            const float bv = bias[n];
            #pragma unroll
            for (int r = 0; r < 4; ++r) {
                const int m = bm + wm * 64 + mi * 16 + lg * 4 + r;
                const float val = acc[mi][nj][r] + bv;
                size_t idx;
                if (MODE == 1) {
                    idx = (size_t)((m >> 11) * NH_ + (n >> 6)) * (T_ * HS_)
                        + (size_t)(m & (T_ - 1)) * HS_ + (n & (HS_ - 1));
                } else {
                    idx = (size_t)m * N + n;
                }
                storev(out + idx, val);
            }
        }
    }
}

// ---------------- causal flash attention -----------------------------------
// Folded work balance + block-staged double-buffered K/V in LDS.
// Qh,Kh: [B*NH][T][HS] bf16.  Vt: [B*NH][HS][T] bf16.  Ob: [B][T][NH][HS].
// 8 waves/block; wave w owns q-subtiles s_lo=8*bq+w and s_hi=127-s_lo
// (16 rows each) -> ~constant work per wave. All waves share staged K/V.
// S^T = mfma(K,Q): lane owns q=lr in-softmax; accO rows are q=4*lg+r.
__global__ __launch_bounds__(512, 4) void attn_kernel(
    const bf16* __restrict__ Qh, const bf16* __restrict__ Kh,
    const bf16* __restrict__ Vt, bf16* __restrict__ Ob)
{
    __shared__ __align__(16) char Ks[2][8192];   // 64 rows x 128B, chunk-swizzled
    __shared__ __align__(16) char Vs[2][8192];
    __shared__ __align__(16) char Ps[8][2][2048];

    const int tid  = threadIdx.x;
    const int lane = tid & 63;
    const int w    = tid >> 6;            // 0..7
    const int lg = lane >> 4, lr = lane & 15;
    const int bh = blockIdx.x;            // b*NH + h
    const int bq = blockIdx.y;            // 0..7
    const size_t hb = (size_t)bh * (T_ * HS_);

    const int s_lo = bq * 8 + w;          // 0..63
    const int s_hi = 127 - s_lo;          // 64..127
    const int qbase[2] = { s_lo * 16, s_hi * 16 };
    const int last_t[2] = { s_lo >> 2, s_hi >> 2 };
    const int nt = 32 - 2 * bq;           // tiles staged by this block

    const int swzp = (lr & 7) << 4;       // P-tile row swizzle
    const float SC = 0.125f * 1.44269504088896f;

    // staging assignment: thread handles row = tid>>3, chunk = tid&7 (16B)
    const int strow = tid >> 3;           // 0..63
    const int stch  = tid & 7;            // 0..7
    const int stdst = strow * 128 + ((stch ^ (strow & 7)) << 4);
    const bf16* gK = Kh + hb + (size_t)strow * HS_ + stch * 8;
    const bf16* gV = Vt + hb + (size_t)strow * T_  + stch * 8;

    bf16x8 qf[2][2];
    #pragma unroll
    for (int qs = 0; qs < 2; ++qs)
        #pragma unroll
        for (int kfi = 0; kfi < 2; ++kfi)
            qf[qs][kfi] = *(const bf16x8*)(Qh + hb + (size_t)(qbase[qs] + lr) * HS_ + kfi * 32 + lg * 8);

    f32x4 accO[2][4] = {};
    float m_s[2] = {-1e30f, -1e30f};
    float l_s[2] = {0.f, 0.f};
    char* pwq[2] = {&Ps[w][0][0], &Ps[w][1][0]};

    // prologue: stage tile 0
    uint4 kst = *(const uint4*)(gK);
    uint4 vst = *(const uint4*)(gV);
    *(uint4*)(&Ks[0][stdst]) = kst;
    *(uint4*)(&Vs[0][stdst]) = vst;
    __syncthreads();

    int c = 0;
    for (int t = 0; t < nt; ++t) {
        // issue next-tile global loads early (latency hides under compute)
        if (t + 1 < nt) {
            kst = *(const uint4*)(gK + (size_t)(t + 1) * 64 * HS_);
            vst = *(const uint4*)(gV + (t + 1) * 64);
        }
        const int j0 = t * 64;
        const char* Kc = &Ks[c][0];
        const char* Vc = &Vs[c][0];
        const bool act[2] = { t <= last_t[0], t <= last_t[1] };

        // ---- K fragments from LDS ----
        bf16x8 kfr[4][2];
        #pragma unroll
        for (int s = 0; s < 4; ++s)
            #pragma unroll
            for (int kfi = 0; kfi < 2; ++kfi)
                kfr[s][kfi] = *(const bf16x8*)(Kc + (s * 16 + lr) * 128 + (((kfi * 4 + lg) ^ (lr & 7)) << 4));

        #pragma unroll
        for (int qs = 0; qs < 2; ++qs) {
            if (!act[qs]) continue;
            // S^T: col=q (lane&15), row=k-within-16 (4*lg+r)
            f32x4 st[4];
            #pragma unroll
            for (int s = 0; s < 4; ++s) {
                f32x4 a = {};
                #pragma unroll
                for (int kfi = 0; kfi < 2; ++kfi)
                    a = mfma16(kfr[s][kfi], qf[qs][kfi], a);
                st[s] = a;
            }
            float p[4][4];
            #pragma unroll
            for (int s = 0; s < 4; ++s)
                #pragma unroll
                for (int r = 0; r < 4; ++r)
                    p[s][r] = st[s][r] * SC;
            if (t == last_t[qs]) {        // diagonal tile: causal mask
                const int q = qbase[qs] + lr;
                #pragma unroll
                for (int s = 0; s < 4; ++s)
                    #pragma unroll
                    for (int r = 0; r < 4; ++r)
                        if (j0 + s * 16 + 4 * lg + r > q) p[s][r] = -1e30f;
            }
            // row max: in-lane tree + 2 cross-group shuffles (row = q = lr)
            float mx0 = fmaxf(fmaxf(p[0][0], p[0][1]), fmaxf(p[0][2], p[0][3]));
            float mx1 = fmaxf(fmaxf(p[1][0], p[1][1]), fmaxf(p[1][2], p[1][3]));
            float mx2 = fmaxf(fmaxf(p[2][0], p[2][1]), fmaxf(p[2][2], p[2][3]));
            float mx3 = fmaxf(fmaxf(p[3][0], p[3][1]), fmaxf(p[3][2], p[3][3]));
            float mx = fmaxf(fmaxf(mx0, mx1), fmaxf(mx2, mx3));
            mx = fmaxf(mx, __shfl_xor(mx, 16));
            mx = fmaxf(mx, __shfl_xor(mx, 32));
            const float mnew = fmaxf(m_s[qs], mx);
            const float sf = fexp2(m_s[qs] - mnew);
            m_s[qs] = mnew;
            float rs = 0.f;
            #pragma unroll
            for (int s = 0; s < 4; ++s)
                #pragma unroll
                for (int r = 0; r < 4; ++r) {
                    p[s][r] = fexp2(p[s][r] - mnew);
                    rs += p[s][r];
                }
            rs += __shfl_xor(rs, 16);
            rs += __shfl_xor(rs, 32);
            l_s[qs] = l_s[qs] * sf + rs;
            // redistribute sf to accO rows (accO row r is q=4*lg+r, owner lane 4*lg+r)
            f32x4 sfv;
            #pragma unroll
            for (int r = 0; r < 4; ++r)
                sfv[r] = __shfl(sf, 4 * lg + r);
            #pragma unroll
            for (int d = 0; d < 4; ++d)
                accO[qs][d] *= sfv;
            // pack 4 consecutive-k bf16, write 8B (swizzled)
            #pragma unroll
            for (int s = 0; s < 4; ++s) {
                uint2 pk;
                pk.x = (uint16_t)bf16bits(p[s][0]) | ((uint32_t)(uint16_t)bf16bits(p[s][1]) << 16);
                pk.y = (uint16_t)bf16bits(p[s][2]) | ((uint32_t)(uint16_t)bf16bits(p[s][3]) << 16);
                *(uint2*)(pwq[qs] + ((lr * 128 + s * 32 + lg * 8) ^ swzp)) = pk;
            }
        }
        __builtin_amdgcn_wave_barrier();

        // ---- V fragments from LDS, then PV ----
        bf16x8 vfr[4][2];
        #pragma unroll
        for (int d = 0; d < 4; ++d)
            #pragma unroll
            for (int kfi = 0; kfi < 2; ++kfi)
                vfr[d][kfi] = *(const bf16x8*)(Vc + (d * 16 + lr) * 128 + (((kfi * 4 + lg) ^ (lr & 7)) << 4));

        #pragma unroll
        for (int qs = 0; qs < 2; ++qs) {
            if (!act[qs]) continue;
            bf16x8 aP[2];
            #pragma unroll
            for (int kfi = 0; kfi < 2; ++kfi)
                aP[kfi] = *(const bf16x8*)(pwq[qs] + ((lr * 128 + kfi * 64 + lg * 16) ^ swzp));
            #pragma unroll
            for (int d = 0; d < 4; ++d)
                #pragma unroll
                for (int kfi = 0; kfi < 2; ++kfi)
                    accO[qs][d] = mfma16(aP[kfi], vfr[d][kfi], accO[qs][d]);
        }

        // ---- write next tile's staged regs into other buffer ----
        if (t + 1 < nt) {
            *(uint4*)(&Ks[c ^ 1][stdst]) = kst;
            *(uint4*)(&Vs[c ^ 1][stdst]) = vst;
        }
        __syncthreads();
        c ^= 1;
    }

    // epilogue: redistribute l (owner lane = 4*lg+r), write Ob[b][t][h][d]
    const int b = bh >> 4, h = bh & 15;
    #pragma unroll
    for (int qs = 0; qs < 2; ++qs) {
        float lsv[4];
        #pragma unroll
        for (int r = 0; r < 4; ++r)
            lsv[r] = __shfl(l_s[qs], 4 * lg + r);
        #pragma unroll
        for (int d = 0; d < 4; ++d)
            #pragma unroll
            for (int r = 0; r < 4; ++r) {
                const int q = qbase[qs] + 4 * lg + r;
                const float o = accO[qs][d][r] / lsv[r];
                Ob[(((size_t)b * T_ + q) * NH_ + h) * HS_ + d * 16 + lr] = __float2bfloat16(o);
            }
    }
}

// ---------------- launch ----------------------------------------------------
extern "C" void kernel_launch(void* const* d_in, const int* in_sizes, int n_in,
                              void* d_out, int out_size, void* d_ws, size_t ws_size,
                              hipStream_t stream)
{
    (void)in_sizes; (void)n_in; (void)out_size; (void)ws_size;
    const float* Xq = (const float*)d_in[0];
    const float* Xk = (const float*)d_in[1];
    const float* Xv = (const float*)d_in[2];
    // d_in[3] = mask: known causal triu(k=1); implemented analytically.
    const float* Wq = (const float*)d_in[4];
    const float* bq = (const float*)d_in[5];
    const float* Wk = (const float*)d_in[6];
    const float* bk = (const float*)d_in[7];
    const float* Wv = (const float*)d_in[8];
    const float* bv = (const float*)d_in[9];
    const float* Wo = (const float*)d_in[10];
    const float* bo = (const float*)d_in[11];

    char* ws = (char*)d_ws;
    bf16* WqT = (bf16*)(ws + ((size_t)0  << 20));  // 2MB each (bf16 transposed)
    bf16* WkT = (bf16*)(ws + ((size_t)2  << 20));
    bf16* WvT = (bf16*)(ws + ((size_t)4  << 20));
    bf16* WoT = (bf16*)(ws + ((size_t)6  << 20));
    bf16* Qh  = (bf16*)(ws + ((size_t)8  << 20));  // 16MB each
    bf16* Kh  = (bf16*)(ws + ((size_t)24 << 20));
    bf16* Vh  = (bf16*)(ws + ((size_t)40 << 20));
    bf16* VtG = (bf16*)(ws + ((size_t)56 << 20));
    bf16* Ob  = (bf16*)(ws + ((size_t)72 << 20));  // ends at 88MB

    dim3 blk(256);
    transpose_kernel<float><<<dim3(16, 16, 1), blk, 0, stream>>>(Wq, WqT, 1024, 1024);
    transpose_kernel<float><<<dim3(16, 16, 1), blk, 0, stream>>>(Wk, WkT, 1024, 1024);
    transpose_kernel<float><<<dim3(16, 16, 1), blk, 0, stream>>>(Wv, WvT, 1024, 1024);
    transpose_kernel<float><<<dim3(16, 16, 1), blk, 0, stream>>>(Wo, WoT, 1024, 1024);

    gemm_bias_kernel<1, float, bf16><<<dim3(64, 8), blk, 0, stream>>>(Xq, WqT, bq, Qh, 8192, 1024, 1024);
    gemm_bias_kernel<1, float, bf16><<<dim3(64, 8), blk, 0, stream>>>(Xk, WkT, bk, Kh, 8192, 1024, 1024);
    gemm_bias_kernel<1, float, bf16><<<dim3(64, 8), blk, 0, stream>>>(Xv, WvT, bv, Vh, 8192, 1024, 1024);

    // per-head V transpose: [bh][t][d] -> [bh][d][t]
    transpose_kernel<bf16><<<dim3(1, 32, B_ * NH_), blk, 0, stream>>>(Vh, VtG, T_, HS_);

    attn_kernel<<<dim3(64, 8), dim3(512), 0, stream>>>(Qh, Kh, VtG, Ob);

    // final projection written as FLOAT32 (reference output dtype)
    gemm_bias_kernel<0, bf16, float><<<dim3(64, 8), blk, 0, stream>>>(Ob, WoT, bo, (float*)d_out, 8192, 1024, 1024);
}